// Round 7
// baseline (323.211 us; speedup 1.0000x reference)
//
#include <hip/hip_runtime.h>

#define H 128

typedef __attribute__((ext_vector_type(8))) short bf16x8;
typedef __attribute__((ext_vector_type(4))) float f32x4;
typedef unsigned int uint;
typedef unsigned short ushort;

__device__ __forceinline__ ushort f2bf(float f) {
    uint u = __builtin_bit_cast(uint, f);
    uint r = u + 0x7FFFu + ((u >> 16) & 1u);
    return (ushort)(r >> 16);
}
__device__ __forceinline__ float bf_lo(uint u) {
    return __builtin_bit_cast(float, u << 16);
}
__device__ __forceinline__ float bf_hi(uint u) {
    return __builtin_bit_cast(float, u & 0xFFFF0000u);
}

// =======================================================================
// CSR build, bucket-local. bucket = row>>10 (NB buckets), edge chunks of
// 4096 (NBLK blocks).
// =======================================================================

__global__ void bucket_hist(const int* __restrict__ ei, int E, int NB, int NBLK,
                            int* __restrict__ cntg) {
    __shared__ int cnt[1024];
    int blk = blockIdx.x, t = threadIdx.x;
    for (int b = t; b < NB; b += 256) cnt[b] = 0;
    __syncthreads();
    int lo = blk << 12, hi = min(lo + 4096, E);
    for (int e = lo + t; e < hi; e += 256) atomicAdd(&cnt[ei[e] >> 10], 1);
    __syncthreads();
    for (int b = t; b < NB; b += 256) cntg[b * NBLK + blk] = cnt[b];
}

__global__ void scan_reduce(const int* __restrict__ src, int* __restrict__ bsum, int M) {
    __shared__ int sm[256];
    int lo = blockIdx.x * 512;
    int t = threadIdx.x;
    int a = (lo + t < M) ? src[lo + t] : 0;
    int b = (lo + 256 + t < M) ? src[lo + 256 + t] : 0;
    sm[t] = a + b;
    __syncthreads();
    for (int d = 128; d; d >>= 1) {
        if (t < d) sm[t] += sm[t + d];
        __syncthreads();
    }
    if (t == 0) bsum[blockIdx.x] = sm[0];
}

__global__ void scan_bsums(int* __restrict__ bsum, int* __restrict__ dst, int B, int M) {
    __shared__ int s[1024];
    int t = threadIdx.x;
    int v = (t < B) ? bsum[t] : 0;
    s[t] = v;
    __syncthreads();
    for (int d = 1; d < 1024; d <<= 1) {
        int u = (t >= d) ? s[t - d] : 0;
        __syncthreads();
        s[t] += u;
        __syncthreads();
    }
    if (t < B) bsum[t] = s[t] - v;
    if (t == 1023) dst[M] = s[1023];
}

__global__ void scan_write(const int* __restrict__ src, const int* __restrict__ bsum,
                           int* __restrict__ dst, int M) {
    __shared__ int sm[256];
    int lo = blockIdx.x * 512;
    int t = threadIdx.x;
    int i0 = lo + 2 * t, i1 = i0 + 1;
    int d0 = (i0 < M) ? src[i0] : 0;
    int d1 = (i1 < M) ? src[i1] : 0;
    int p = d0 + d1;
    sm[t] = p;
    __syncthreads();
    for (int d = 1; d < 256; d <<= 1) {
        int u = (t >= d) ? sm[t - d] : 0;
        __syncthreads();
        sm[t] += u;
        __syncthreads();
    }
    int ex = sm[t] - p + bsum[blockIdx.x];
    if (i0 < M) dst[i0] = ex;
    if (i1 < M) dst[i1] = ex + d0;
}

__global__ void bucket_scatter(const int* __restrict__ ei, int E, int NB, int NBLK,
                               const int* __restrict__ ebase, int2* __restrict__ ebuf) {
    __shared__ int lcnt[1024];
    __shared__ int lbase[1024];
    int blk = blockIdx.x, t = threadIdx.x;
    for (int b = t; b < NB; b += 256) {
        lcnt[b] = 0;
        lbase[b] = ebase[b * NBLK + blk];
    }
    __syncthreads();
    int lo = blk << 12, hi = min(lo + 4096, E);
    for (int e = lo + t; e < hi; e += 256) {
        int r = ei[e], c = ei[E + e];
        int b = r >> 10;
        int pos = lbase[b] + atomicAdd(&lcnt[b], 1);
        ebuf[pos] = make_int2(r, c);
    }
}

__global__ __launch_bounds__(1024)
void bucket_csr(const int2* __restrict__ ebuf, const int* __restrict__ ebase,
                int NB, int NBLK, int E, int N,
                int* __restrict__ deg, int* __restrict__ off,
                int* __restrict__ colss) {
    __shared__ int rcnt[1024], rloff[1024];
    int b = blockIdx.x, t = threadIdx.x;
    int rowbase = b << 10;
    int rs = ebase[b * NBLK];
    int re = (b == NB - 1) ? E : ebase[(b + 1) * NBLK];
    rcnt[t] = 0;
    __syncthreads();
    for (int e = rs + t; e < re; e += 1024) atomicAdd(&rcnt[ebuf[e].x - rowbase], 1);
    __syncthreads();
    int v = rcnt[t];
    rloff[t] = v;
    __syncthreads();
    for (int d = 1; d < 1024; d <<= 1) {
        int u = (t >= d) ? rloff[t - d] : 0;
        __syncthreads();
        rloff[t] += u;
        __syncthreads();
    }
    int ex = rloff[t] - v;
    int row = rowbase + t;
    if (row < N) {
        deg[row] = v;
        off[row] = rs + ex;
    }
    if (b == NB - 1 && t == 0) off[N] = E;
    __syncthreads();
    rloff[t] = ex;
    rcnt[t] = 0;
    __syncthreads();
    for (int e = rs + t; e < re; e += 1024) {
        int2 rc = ebuf[e];
        int lr = rc.x - rowbase;
        int pz = atomicAdd(&rcnt[lr], 1);
        colss[rs + rloff[lr] + pz] = rc.y;
    }
}

// c_i[k] = sum_j W3[i][k][j] * relu(W4[i][j])
__global__ void cvec_kernel(const float* __restrict__ W3, const float* __restrict__ W4,
                            float* __restrict__ cvec) {
    int i = blockIdx.x, k = threadIdx.x;
    const float* w3 = W3 + i * H * H + k * H;
    const float* w4 = W4 + i * H;
    float s = 0.f;
    for (int j = 0; j < H; ++j) s += w3[j] * fmaxf(w4[j], 0.f);
    cvec[i * H + k] = s;
}

__global__ void cast_bf16(const float* __restrict__ in, ushort* __restrict__ outp, int n8) {
    int i = blockIdx.x * blockDim.x + threadIdx.x;
    if (i >= n8) return;
    const float4* in4 = (const float4*)in;
    float4 a = in4[2 * i], b = in4[2 * i + 1];
    uint4 o;
    o.x = (uint)f2bf(a.x) | ((uint)f2bf(a.y) << 16);
    o.y = (uint)f2bf(a.z) | ((uint)f2bf(a.w) << 16);
    o.z = (uint)f2bf(b.x) | ((uint)f2bf(b.y) << 16);
    o.w = (uint)f2bf(b.z) | ((uint)f2bf(b.w) << 16);
    ((uint4*)outp)[i] = o;
}

// =======================================================================
// multi_xproj v2: A-tile ONLY in LDS (32KB, f32->bf16 on stage), stored as
// two half-K planes [kc][128 r][8 slot] (128B row stride -> 2-way max bank
// aliasing = free). W fragments read DIRECT from global (L1/L2-resident
// 32KB panel). No barriers after staging; 3 hops reuse A4 read-only.
// =======================================================================

__global__ __launch_bounds__(256)
void multi_xproj(const float* __restrict__ x, const ushort* __restrict__ W1b,
                 const int* __restrict__ deg, const float* __restrict__ cvec,
                 ushort* __restrict__ h, ushort* __restrict__ bias,
                 float* __restrict__ outf, int N, int HOP)
{
    __shared__ uint4 A4[2048];              // [kc][128][8] 32KB
    int t = threadIdx.x;
    int wv = t >> 6, l = t & 63;
    int lg = l >> 4, lr = l & 15;
    int rowBase = blockIdx.x * 128;

    const float4* xg = (const float4*)x;    // 32 float4 per row
    const uint4* Wg = (const uint4*)W1b;    // rows of 16 uint4

    // ---- stage A tile, f32 -> bf16 ----
#pragma unroll
    for (int it = 0; it < 8; ++it) {
        int idx = it * 256 + t;             // 0..2047
        int r = idx >> 4, sg = idx & 15;
        int kc = sg >> 3, s = sg & 7;
        int gr = rowBase + r;
        uint4 v = make_uint4(0, 0, 0, 0);
        if (gr < N) {
            float4 a = xg[(size_t)gr * 32 + 2 * sg];
            float4 b = xg[(size_t)gr * 32 + 2 * sg + 1];
            v.x = (uint)f2bf(a.x) | ((uint)f2bf(a.y) << 16);
            v.y = (uint)f2bf(a.z) | ((uint)f2bf(a.w) << 16);
            v.z = (uint)f2bf(b.x) | ((uint)f2bf(b.y) << 16);
            v.w = (uint)f2bf(b.z) | ((uint)f2bf(b.w) << 16);
        }
        A4[kc * 1024 + r * 8 + (s ^ (r & 7))] = v;
    }
    __syncthreads();

    float dreg[2][4];
#pragma unroll
    for (int rt = 0; rt < 2; ++rt)
#pragma unroll
        for (int jj = 0; jj < 4; ++jj) {
            int gr = rowBase + wv * 32 + rt * 16 + lg * 4 + jj;
            dreg[rt][jj] = (gr < N) ? (float)deg[gr] : 0.f;
        }

    for (int j = 0; j < HOP; ++j) {
        f32x4 acc[2][8];
#pragma unroll
        for (int rt = 0; rt < 2; ++rt)
#pragma unroll
            for (int ct = 0; ct < 8; ++ct) acc[rt][ct] = (f32x4){0.f, 0.f, 0.f, 0.f};

#pragma unroll
        for (int ks = 0; ks < 4; ++ks) {
            int slot = ks * 4 + lg, kc = slot >> 3, s8 = slot & 7;
            bf16x8 af[2];
#pragma unroll
            for (int rt = 0; rt < 2; ++rt) {
                int r = wv * 32 + rt * 16 + lr;
                af[rt] = *(const bf16x8*)&A4[kc * 1024 + r * 8 + (s8 ^ (r & 7))];
            }
            bf16x8 bfr[8];
#pragma unroll
            for (int ct = 0; ct < 8; ++ct) {
                uint4 wv4 = Wg[((size_t)j * 128 + ct * 16 + lr) * 16 + slot];
                bfr[ct] = *(const bf16x8*)&wv4;
            }
#pragma unroll
            for (int rt = 0; rt < 2; ++rt)
#pragma unroll
                for (int ct = 0; ct < 8; ++ct)
                    acc[rt][ct] = __builtin_amdgcn_mfma_f32_16x16x32_bf16(
                        af[rt], bfr[ct], acc[rt][ct], 0, 0, 0);
        }

        float cv[8];
#pragma unroll
        for (int ct = 0; ct < 8; ++ct) cv[ct] = cvec[j * H + ct * 16 + lr];
#pragma unroll
        for (int rt = 0; rt < 2; ++rt) {
#pragma unroll
            for (int jj = 0; jj < 4; ++jj) {
                int gr = rowBase + wv * 32 + rt * 16 + lg * 4 + jj;
                if (gr < N) {
                    float d = dreg[rt][jj];
#pragma unroll
                    for (int ct = 0; ct < 8; ++ct) {
                        int gc = ct * 16 + lr;
                        float v = acc[rt][ct][jj] + d * cv[ct];
                        if (j == 0) {
                            v = fmaxf(v, 0.f);
                            if (HOP == 1) outf[(size_t)gr * H + gc] = v;
                            else h[(size_t)gr * H + gc] = f2bf(v);
                        } else {
                            bias[(size_t)(j - 1) * N * H + (size_t)gr * H + gc] = f2bf(v);
                        }
                    }
                }
            }
        }
    }
}

// =======================================================================
// gemm_mfma v2 (p = h@W2_i^T): A full-K in LDS ([kc][128][8] planes),
// W direct from global, single barrier.
// =======================================================================

template<int ADD_DEGC, int RELU, int OUT_BF16>
__global__ __launch_bounds__(256)
void gemm_mfma(const ushort* __restrict__ A, const ushort* __restrict__ W,
               const int* __restrict__ deg, const float* __restrict__ cvec,
               void* __restrict__ Cout, int N)
{
    __shared__ uint4 A4[2048];
    int t = threadIdx.x;
    int w = t >> 6, l = t & 63;
    int lg = l >> 4, lr = l & 15;
    int rowBase = blockIdx.x * 128;

    const uint4* Ag = (const uint4*)A;
    const uint4* Wg = (const uint4*)W;

#pragma unroll
    for (int it = 0; it < 8; ++it) {
        int idx = it * 256 + t;
        int r = idx >> 4, sg = idx & 15;
        int kc = sg >> 3, s = sg & 7;
        int gr = rowBase + r;
        uint4 v = make_uint4(0, 0, 0, 0);
        if (gr < N) v = Ag[(size_t)gr * 16 + sg];
        A4[kc * 1024 + r * 8 + (s ^ (r & 7))] = v;
    }
    __syncthreads();

    f32x4 acc[2][8];
#pragma unroll
    for (int rt = 0; rt < 2; ++rt)
#pragma unroll
        for (int ct = 0; ct < 8; ++ct) acc[rt][ct] = (f32x4){0.f, 0.f, 0.f, 0.f};

#pragma unroll
    for (int ks = 0; ks < 4; ++ks) {
        int slot = ks * 4 + lg, kc = slot >> 3, s8 = slot & 7;
        bf16x8 af[2];
#pragma unroll
        for (int rt = 0; rt < 2; ++rt) {
            int r = w * 32 + rt * 16 + lr;
            af[rt] = *(const bf16x8*)&A4[kc * 1024 + r * 8 + (s8 ^ (r & 7))];
        }
        bf16x8 bfr[8];
#pragma unroll
        for (int ct = 0; ct < 8; ++ct) {
            uint4 wv4 = Wg[(ct * 16 + lr) * 16 + slot];
            bfr[ct] = *(const bf16x8*)&wv4;
        }
#pragma unroll
        for (int rt = 0; rt < 2; ++rt)
#pragma unroll
            for (int ct = 0; ct < 8; ++ct)
                acc[rt][ct] = __builtin_amdgcn_mfma_f32_16x16x32_bf16(
                    af[rt], bfr[ct], acc[rt][ct], 0, 0, 0);
    }

    float cv[8];
    if (ADD_DEGC) {
#pragma unroll
        for (int ct = 0; ct < 8; ++ct) cv[ct] = cvec[ct * 16 + lr];
    }
#pragma unroll
    for (int rt = 0; rt < 2; ++rt) {
#pragma unroll
        for (int j = 0; j < 4; ++j) {
            int gr = rowBase + w * 32 + rt * 16 + lg * 4 + j;
            if (gr < N) {
                float d = ADD_DEGC ? (float)deg[gr] : 0.f;
#pragma unroll
                for (int ct = 0; ct < 8; ++ct) {
                    int gc = ct * 16 + lr;
                    float v = acc[rt][ct][j];
                    if (ADD_DEGC) v += d * cv[ct];
                    if (RELU) v = fmaxf(v, 0.f);
                    if (OUT_BF16) ((ushort*)Cout)[(size_t)gr * H + gc] = f2bf(v);
                    else ((float*)Cout)[(size_t)gr * H + gc] = v;
                }
            }
        }
    }
}

// =======================================================================
// aggregation: dst[n] = relu(biasb[n] + sum_{e in row n} p[cols[e]])
// =======================================================================

template<int OUT_BF16>
__global__ void aggregate_relu3(const ushort* __restrict__ biasb, const ushort* __restrict__ p,
                                const int* __restrict__ off, const int* __restrict__ cols,
                                void* __restrict__ dst, int N)
{
    int node = blockIdx.x * 4 + (threadIdx.x >> 6);
    if (node >= N) return;
    int l = threadIdx.x & 63;
    int s = off[node], e = off[node + 1];
    const uint* pu = (const uint*)p;     // [N][64]
    float ax = 0.f, ay = 0.f;
    int i = s;
    for (; i + 8 <= e; i += 8) {
        uint v0 = pu[(size_t)cols[i]     * 64 + l];
        uint v1 = pu[(size_t)cols[i + 1] * 64 + l];
        uint v2 = pu[(size_t)cols[i + 2] * 64 + l];
        uint v3 = pu[(size_t)cols[i + 3] * 64 + l];
        uint v4 = pu[(size_t)cols[i + 4] * 64 + l];
        uint v5 = pu[(size_t)cols[i + 5] * 64 + l];
        uint v6 = pu[(size_t)cols[i + 6] * 64 + l];
        uint v7 = pu[(size_t)cols[i + 7] * 64 + l];
        ax += bf_lo(v0) + bf_lo(v1) + bf_lo(v2) + bf_lo(v3)
            + bf_lo(v4) + bf_lo(v5) + bf_lo(v6) + bf_lo(v7);
        ay += bf_hi(v0) + bf_hi(v1) + bf_hi(v2) + bf_hi(v3)
            + bf_hi(v4) + bf_hi(v5) + bf_hi(v6) + bf_hi(v7);
    }
    for (; i + 4 <= e; i += 4) {
        uint v0 = pu[(size_t)cols[i]     * 64 + l];
        uint v1 = pu[(size_t)cols[i + 1] * 64 + l];
        uint v2 = pu[(size_t)cols[i + 2] * 64 + l];
        uint v3 = pu[(size_t)cols[i + 3] * 64 + l];
        ax += bf_lo(v0) + bf_lo(v1) + bf_lo(v2) + bf_lo(v3);
        ay += bf_hi(v0) + bf_hi(v1) + bf_hi(v2) + bf_hi(v3);
    }
    for (; i < e; ++i) {
        uint v = pu[(size_t)cols[i] * 64 + l];
        ax += bf_lo(v);
        ay += bf_hi(v);
    }
    uint bb = ((const uint*)biasb)[(size_t)node * 64 + l];
    float ox = fmaxf(bf_lo(bb) + ax, 0.f);
    float oy = fmaxf(bf_hi(bb) + ay, 0.f);
    if (OUT_BF16) {
        ((uint*)dst)[(size_t)node * 64 + l] = (uint)f2bf(ox) | ((uint)f2bf(oy) << 16);
    } else {
        ((float2*)dst)[(size_t)node * 64 + l] = make_float2(ox, oy);
    }
}

// =======================================================================
// launch
// =======================================================================

extern "C" void kernel_launch(void* const* d_in, const int* in_sizes, int n_in,
                              void* d_out, int out_size, void* d_ws, size_t ws_size,
                              hipStream_t stream)
{
    const float* x  = (const float*)d_in[0];
    const int*   ei = (const int*)d_in[1];
    const float* W1 = (const float*)d_in[2];
    const float* W2 = (const float*)d_in[3];
    const float* W3 = (const float*)d_in[4];
    const float* W4 = (const float*)d_in[5];
    int N   = in_sizes[0] / H;
    int E   = in_sizes[1] / 2;
    int HOP = in_sizes[2] / (H * H);

    int NB   = (N + 1023) >> 10;
    int NBLK = (E + 4095) >> 12;
    int M    = NB * NBLK;

    char* ws = (char*)d_ws;
    int*   deg   = (int*)ws;                  // N
    int*   off   = deg + N;                   // N+1
    int*   colss = off + N + 1;               // E
    int*   cntg  = colss + E;                 // M
    int*   ebase = cntg + M;                  // M+1
    int*   bsum  = ebase + M + 1;             // <=1024
    float* cvec  = (float*)(bsum + 1024);     // HOP*H
    size_t fo = (((size_t)((char*)(cvec + HOP * H) - ws)) + 255) & ~(size_t)255;
    int2*  ebuf  = (int2*)(ws + fo);          // E int2
    ushort* W1b  = (ushort*)(ebuf + E);       // HOP*H*H
    ushort* W2b  = W1b + (size_t)HOP * H * H; // HOP*H*H
    ushort* p    = W2b + (size_t)HOP * H * H; // N*H
    ushort* h    = p + (size_t)N * H;         // N*H
    ushort* bias = h + (size_t)N * H;         // (HOP-1)*N*H

    // ---- CSR build ----
    bucket_hist<<<NBLK, 256, 0, stream>>>(ei, E, NB, NBLK, cntg);
    int Bq = (M + 511) / 512;
    scan_reduce<<<Bq, 256, 0, stream>>>(cntg, bsum, M);
    scan_bsums<<<1, 1024, 0, stream>>>(bsum, ebase, Bq, M);
    scan_write<<<Bq, 256, 0, stream>>>(cntg, bsum, ebase, M);
    bucket_scatter<<<NBLK, 256, 0, stream>>>(ei, E, NB, NBLK, ebase, ebuf);
    bucket_csr<<<NB, 1024, 0, stream>>>(ebuf, ebase, NB, NBLK, E, N, deg, off, colss);

    cvec_kernel<<<HOP, H, 0, stream>>>(W3, W4, cvec);

    // ---- weight casts (tiny) ----
    int nw8 = HOP * H * H / 8;
    cast_bf16<<<(nw8 + 255) / 256, 256, 0, stream>>>(W1, W1b, nw8);
    cast_bf16<<<(nw8 + 255) / 256, 256, 0, stream>>>(W2, W2b, nw8);

    int gblocks = (N + 127) / 128;
    float* out = (float*)d_out;

    // h = relu(x@W1[0]^T + deg*c0); bias[j-1] = x@W1[j]^T + deg*c_j
    multi_xproj<<<gblocks, 256, 0, stream>>>(x, W1b, deg, cvec, h, bias, out, N, HOP);
    if (HOP == 1) return;

    for (int i = 1; i < HOP; ++i) {
        int last = (i == HOP - 1);
        // p = h @ W2[i]^T (bf16)
        gemm_mfma<0, 0, 1><<<gblocks, 256, 0, stream>>>(h, W2b + (size_t)i * H * H,
                                                        nullptr, nullptr, p, N);
        // dst = relu(bias[i-1] + A p)
        if (last)
            aggregate_relu3<0><<<(N + 3) / 4, 256, 0, stream>>>(bias + (size_t)(i - 1) * N * H,
                                                                p, off, colss, out, N);
        else
            aggregate_relu3<1><<<(N + 3) / 4, 256, 0, stream>>>(bias + (size_t)(i - 1) * N * H,
                                                                p, off, colss, h, N);
    }
}

// Round 8
// 260.671 us; speedup vs baseline: 1.2399x; 1.2399x over previous
//
#include <hip/hip_runtime.h>

#define H 128

typedef __attribute__((ext_vector_type(8))) short bf16x8;
typedef __attribute__((ext_vector_type(4))) float f32x4;
typedef unsigned int uint;
typedef unsigned short ushort;

__device__ __forceinline__ ushort f2bf(float f) {
    uint u = __builtin_bit_cast(uint, f);
    uint r = u + 0x7FFFu + ((u >> 16) & 1u);
    return (ushort)(r >> 16);
}
__device__ __forceinline__ float bf_lo(uint u) {
    return __builtin_bit_cast(float, u << 16);
}
__device__ __forceinline__ float bf_hi(uint u) {
    return __builtin_bit_cast(float, u & 0xFFFF0000u);
}

// =======================================================================
// CSR build, bucket-local. bucket = row>>10 (NB buckets), edge chunks of
// 4096 (NBLK blocks).
// =======================================================================

__global__ void bucket_hist(const int* __restrict__ ei, int E, int NB, int NBLK,
                            int* __restrict__ cntg) {
    __shared__ int cnt[1024];
    int blk = blockIdx.x, t = threadIdx.x;
    for (int b = t; b < NB; b += 256) cnt[b] = 0;
    __syncthreads();
    int lo = blk << 12, hi = min(lo + 4096, E);
    for (int e = lo + t; e < hi; e += 256) atomicAdd(&cnt[ei[e] >> 10], 1);
    __syncthreads();
    for (int b = t; b < NB; b += 256) cntg[b * NBLK + blk] = cnt[b];
}

__global__ void scan_reduce(const int* __restrict__ src, int* __restrict__ bsum, int M) {
    __shared__ int sm[256];
    int lo = blockIdx.x * 512;
    int t = threadIdx.x;
    int a = (lo + t < M) ? src[lo + t] : 0;
    int b = (lo + 256 + t < M) ? src[lo + 256 + t] : 0;
    sm[t] = a + b;
    __syncthreads();
    for (int d = 128; d; d >>= 1) {
        if (t < d) sm[t] += sm[t + d];
        __syncthreads();
    }
    if (t == 0) bsum[blockIdx.x] = sm[0];
}

__global__ void scan_bsums(int* __restrict__ bsum, int* __restrict__ dst, int B, int M) {
    __shared__ int s[1024];
    int t = threadIdx.x;
    int v = (t < B) ? bsum[t] : 0;
    s[t] = v;
    __syncthreads();
    for (int d = 1; d < 1024; d <<= 1) {
        int u = (t >= d) ? s[t - d] : 0;
        __syncthreads();
        s[t] += u;
        __syncthreads();
    }
    if (t < B) bsum[t] = s[t] - v;
    if (t == 1023) dst[M] = s[1023];
}

__global__ void scan_write(const int* __restrict__ src, const int* __restrict__ bsum,
                           int* __restrict__ dst, int M) {
    __shared__ int sm[256];
    int lo = blockIdx.x * 512;
    int t = threadIdx.x;
    int i0 = lo + 2 * t, i1 = i0 + 1;
    int d0 = (i0 < M) ? src[i0] : 0;
    int d1 = (i1 < M) ? src[i1] : 0;
    int p = d0 + d1;
    sm[t] = p;
    __syncthreads();
    for (int d = 1; d < 256; d <<= 1) {
        int u = (t >= d) ? sm[t - d] : 0;
        __syncthreads();
        sm[t] += u;
        __syncthreads();
    }
    int ex = sm[t] - p + bsum[blockIdx.x];
    if (i0 < M) dst[i0] = ex;
    if (i1 < M) dst[i1] = ex + d0;
}

__global__ void bucket_scatter(const int* __restrict__ ei, int E, int NB, int NBLK,
                               const int* __restrict__ ebase, int2* __restrict__ ebuf) {
    __shared__ int lcnt[1024];
    __shared__ int lbase[1024];
    int blk = blockIdx.x, t = threadIdx.x;
    for (int b = t; b < NB; b += 256) {
        lcnt[b] = 0;
        lbase[b] = ebase[b * NBLK + blk];
    }
    __syncthreads();
    int lo = blk << 12, hi = min(lo + 4096, E);
    for (int e = lo + t; e < hi; e += 256) {
        int r = ei[e], c = ei[E + e];
        int b = r >> 10;
        int pos = lbase[b] + atomicAdd(&lcnt[b], 1);
        ebuf[pos] = make_int2(r, c);
    }
}

__global__ __launch_bounds__(1024)
void bucket_csr(const int2* __restrict__ ebuf, const int* __restrict__ ebase,
                int NB, int NBLK, int E, int N,
                int* __restrict__ deg, int* __restrict__ off,
                int* __restrict__ colss) {
    __shared__ int rcnt[1024], rloff[1024];
    int b = blockIdx.x, t = threadIdx.x;
    int rowbase = b << 10;
    int rs = ebase[b * NBLK];
    int re = (b == NB - 1) ? E : ebase[(b + 1) * NBLK];
    rcnt[t] = 0;
    __syncthreads();
    for (int e = rs + t; e < re; e += 1024) atomicAdd(&rcnt[ebuf[e].x - rowbase], 1);
    __syncthreads();
    int v = rcnt[t];
    rloff[t] = v;
    __syncthreads();
    for (int d = 1; d < 1024; d <<= 1) {
        int u = (t >= d) ? rloff[t - d] : 0;
        __syncthreads();
        rloff[t] += u;
        __syncthreads();
    }
    int ex = rloff[t] - v;
    int row = rowbase + t;
    if (row < N) {
        deg[row] = v;
        off[row] = rs + ex;
    }
    if (b == NB - 1 && t == 0) off[N] = E;
    __syncthreads();
    rloff[t] = ex;
    rcnt[t] = 0;
    __syncthreads();
    for (int e = rs + t; e < re; e += 1024) {
        int2 rc = ebuf[e];
        int lr = rc.x - rowbase;
        int pz = atomicAdd(&rcnt[lr], 1);
        colss[rs + rloff[lr] + pz] = rc.y;
    }
}

// c_i[k] = sum_j W3[i][k][j] * relu(W4[i][j])
__global__ void cvec_kernel(const float* __restrict__ W3, const float* __restrict__ W4,
                            float* __restrict__ cvec) {
    int i = blockIdx.x, k = threadIdx.x;
    const float* w3 = W3 + i * H * H + k * H;
    const float* w4 = W4 + i * H;
    float s = 0.f;
    for (int j = 0; j < H; ++j) s += w3[j] * fmaxf(w4[j], 0.f);
    cvec[i * H + k] = s;
}

__global__ void cast_bf16(const float* __restrict__ in, ushort* __restrict__ outp, int n8) {
    int i = blockIdx.x * blockDim.x + threadIdx.x;
    if (i >= n8) return;
    const float4* in4 = (const float4*)in;
    float4 a = in4[2 * i], b = in4[2 * i + 1];
    uint4 o;
    o.x = (uint)f2bf(a.x) | ((uint)f2bf(a.y) << 16);
    o.y = (uint)f2bf(a.z) | ((uint)f2bf(a.w) << 16);
    o.z = (uint)f2bf(b.x) | ((uint)f2bf(b.y) << 16);
    o.w = (uint)f2bf(b.z) | ((uint)f2bf(b.w) << 16);
    ((uint4*)outp)[i] = o;
}

// =======================================================================
// gemm_pairs: C[n][j] = sum_{pr<npairs} sum_k A_pr[n][k]*W_pr[j][k]
//                       (+ deg[n]*cvec[j]) (+relu)
// R3-proven structure: A,W both LDS-staged per K-64 chunk, [128 r][8 slot]
// uint4 with slot^(r&7) swizzle (128B row stride -> <=2-way = free).
// K=128 per pair -> 2 chunks per pair, npairs<=2 -> <=4 chunks.
// =======================================================================

template<int RELU, int OUT_BF16>
__global__ __launch_bounds__(256)
void gemm_pairs(const ushort* __restrict__ A0, const ushort* __restrict__ W0,
                const ushort* __restrict__ A1, const ushort* __restrict__ W1,
                int npairs, const int* __restrict__ deg, const float* __restrict__ cvec,
                void* __restrict__ Cout, int N)
{
    __shared__ uint4 A4[1024];
    __shared__ uint4 W4[1024];
    int t = threadIdx.x;
    int w = t >> 6, l = t & 63;
    int lg = l >> 4, lr = l & 15;
    int rowBase = blockIdx.x * 128;

    f32x4 acc[2][8];
#pragma unroll
    for (int rt = 0; rt < 2; ++rt)
#pragma unroll
        for (int ct = 0; ct < 8; ++ct) acc[rt][ct] = (f32x4){0.f, 0.f, 0.f, 0.f};

    for (int pr = 0; pr < npairs; ++pr) {
        const uint4* Ag = (const uint4*)(pr ? A1 : A0);
        const uint4* Wg = (const uint4*)(pr ? W1 : W0);
        for (int kc = 0; kc < 2; ++kc) {
            if (pr || kc) __syncthreads();
#pragma unroll
            for (int it = 0; it < 4; ++it) {
                int idx = it * 256 + t;          // 0..1023
                int r = idx >> 3, s = idx & 7;
                int gr = rowBase + r;
                uint4 v = make_uint4(0, 0, 0, 0);
                if (gr < N) v = Ag[(size_t)gr * 16 + kc * 8 + s];
                A4[r * 8 + (s ^ (r & 7))] = v;
                W4[r * 8 + (s ^ (r & 7))] = Wg[r * 16 + kc * 8 + s];
            }
            __syncthreads();
#pragma unroll
            for (int kk = 0; kk < 2; ++kk) {
                int slot = kk * 4 + lg;
                bf16x8 af[2], bfr[8];
#pragma unroll
                for (int rt = 0; rt < 2; ++rt) {
                    int r = w * 32 + rt * 16 + lr;
                    af[rt] = *(const bf16x8*)&A4[r * 8 + (slot ^ (r & 7))];
                }
#pragma unroll
                for (int ct = 0; ct < 8; ++ct) {
                    int r = ct * 16 + lr;
                    bfr[ct] = *(const bf16x8*)&W4[r * 8 + (slot ^ (r & 7))];
                }
#pragma unroll
                for (int rt = 0; rt < 2; ++rt)
#pragma unroll
                    for (int ct = 0; ct < 8; ++ct)
                        acc[rt][ct] = __builtin_amdgcn_mfma_f32_16x16x32_bf16(
                            af[rt], bfr[ct], acc[rt][ct], 0, 0, 0);
            }
        }
    }

    float cv[8];
#pragma unroll
    for (int ct = 0; ct < 8; ++ct) cv[ct] = cvec[ct * 16 + lr];
#pragma unroll
    for (int rt = 0; rt < 2; ++rt) {
#pragma unroll
        for (int j = 0; j < 4; ++j) {
            int gr = rowBase + w * 32 + rt * 16 + lg * 4 + j;
            if (gr < N) {
                float d = (float)deg[gr];
#pragma unroll
                for (int ct = 0; ct < 8; ++ct) {
                    int gc = ct * 16 + lr;
                    float v = acc[rt][ct][j] + d * cv[ct];
                    if (RELU) v = fmaxf(v, 0.f);
                    if (OUT_BF16) ((ushort*)Cout)[(size_t)gr * H + gc] = f2bf(v);
                    else ((float*)Cout)[(size_t)gr * H + gc] = v;
                }
            }
        }
    }
}

// =======================================================================
// aggregate_sum: s[n] = sum_{e in row n} h[cols[e]]   (bf16 in, bf16 out)
// one wave per node; 8-deep gather unroll for MLP.
// =======================================================================

__global__ void aggregate_sum(const ushort* __restrict__ hsrc,
                              const int* __restrict__ off, const int* __restrict__ cols,
                              ushort* __restrict__ sdst, int N)
{
    int node = blockIdx.x * 4 + (threadIdx.x >> 6);
    if (node >= N) return;
    int l = threadIdx.x & 63;
    int s = off[node], e = off[node + 1];
    const uint* pu = (const uint*)hsrc;  // [N][64]
    float ax = 0.f, ay = 0.f;
    int i = s;
    for (; i + 8 <= e; i += 8) {
        uint v0 = pu[(size_t)cols[i]     * 64 + l];
        uint v1 = pu[(size_t)cols[i + 1] * 64 + l];
        uint v2 = pu[(size_t)cols[i + 2] * 64 + l];
        uint v3 = pu[(size_t)cols[i + 3] * 64 + l];
        uint v4 = pu[(size_t)cols[i + 4] * 64 + l];
        uint v5 = pu[(size_t)cols[i + 5] * 64 + l];
        uint v6 = pu[(size_t)cols[i + 6] * 64 + l];
        uint v7 = pu[(size_t)cols[i + 7] * 64 + l];
        ax += bf_lo(v0) + bf_lo(v1) + bf_lo(v2) + bf_lo(v3)
            + bf_lo(v4) + bf_lo(v5) + bf_lo(v6) + bf_lo(v7);
        ay += bf_hi(v0) + bf_hi(v1) + bf_hi(v2) + bf_hi(v3)
            + bf_hi(v4) + bf_hi(v5) + bf_hi(v6) + bf_hi(v7);
    }
    for (; i + 4 <= e; i += 4) {
        uint v0 = pu[(size_t)cols[i]     * 64 + l];
        uint v1 = pu[(size_t)cols[i + 1] * 64 + l];
        uint v2 = pu[(size_t)cols[i + 2] * 64 + l];
        uint v3 = pu[(size_t)cols[i + 3] * 64 + l];
        ax += bf_lo(v0) + bf_lo(v1) + bf_lo(v2) + bf_lo(v3);
        ay += bf_hi(v0) + bf_hi(v1) + bf_hi(v2) + bf_hi(v3);
    }
    for (; i < e; ++i) {
        uint v = pu[(size_t)cols[i] * 64 + l];
        ax += bf_lo(v);
        ay += bf_hi(v);
    }
    ((uint*)sdst)[(size_t)node * 64 + l] = (uint)f2bf(ax) | ((uint)f2bf(ay) << 16);
}

// =======================================================================
// launch
// =======================================================================

extern "C" void kernel_launch(void* const* d_in, const int* in_sizes, int n_in,
                              void* d_out, int out_size, void* d_ws, size_t ws_size,
                              hipStream_t stream)
{
    const float* x  = (const float*)d_in[0];
    const int*   ei = (const int*)d_in[1];
    const float* W1 = (const float*)d_in[2];
    const float* W2 = (const float*)d_in[3];
    const float* W3 = (const float*)d_in[4];
    const float* W4 = (const float*)d_in[5];
    int N   = in_sizes[0] / H;
    int E   = in_sizes[1] / 2;
    int HOP = in_sizes[2] / (H * H);

    int NB   = (N + 1023) >> 10;
    int NBLK = (E + 4095) >> 12;
    int M    = NB * NBLK;

    char* ws = (char*)d_ws;
    int*   deg   = (int*)ws;                  // N
    int*   off   = deg + N;                   // N+1
    int*   colss = off + N + 1;               // E
    int*   cntg  = colss + E;                 // M
    int*   ebase = cntg + M;                  // M+1
    int*   bsum  = ebase + M + 1;             // <=1024
    float* cvec  = (float*)(bsum + 1024);     // HOP*H
    size_t fo = (((size_t)((char*)(cvec + HOP * H) - ws)) + 255) & ~(size_t)255;
    int2*  ebuf  = (int2*)(ws + fo);          // E int2
    ushort* W1b  = (ushort*)(ebuf + E);       // HOP*H*H
    ushort* W2b  = W1b + (size_t)HOP * H * H; // HOP*H*H
    ushort* xb   = W2b + (size_t)HOP * H * H; // N*H
    ushort* h    = xb + (size_t)N * H;        // N*H
    ushort* sagg = h + (size_t)N * H;         // N*H

    // ---- CSR build ----
    bucket_hist<<<NBLK, 256, 0, stream>>>(ei, E, NB, NBLK, cntg);
    int Bq = (M + 511) / 512;
    scan_reduce<<<Bq, 256, 0, stream>>>(cntg, bsum, M);
    scan_bsums<<<1, 1024, 0, stream>>>(bsum, ebase, Bq, M);
    scan_write<<<Bq, 256, 0, stream>>>(cntg, bsum, ebase, M);
    bucket_scatter<<<NBLK, 256, 0, stream>>>(ei, E, NB, NBLK, ebase, ebuf);
    bucket_csr<<<NB, 1024, 0, stream>>>(ebuf, ebase, NB, NBLK, E, N, deg, off, colss);

    cvec_kernel<<<HOP, H, 0, stream>>>(W3, W4, cvec);

    // ---- casts ----
    int nx8 = N * H / 8;
    cast_bf16<<<(nx8 + 255) / 256, 256, 0, stream>>>(x, xb, nx8);
    int nw8 = HOP * H * H / 8;
    cast_bf16<<<(nw8 + 255) / 256, 256, 0, stream>>>(W1, W1b, nw8);
    cast_bf16<<<(nw8 + 255) / 256, 256, 0, stream>>>(W2, W2b, nw8);

    int gblocks = (N + 127) / 128;
    float* out = (float*)d_out;

    // hop 0: h = relu(xb@W1[0]^T + deg*c0)
    if (HOP == 1) {
        gemm_pairs<1, 0><<<gblocks, 256, 0, stream>>>(xb, W1b, nullptr, nullptr, 1,
                                                      deg, cvec, out, N);
        return;
    }
    gemm_pairs<1, 1><<<gblocks, 256, 0, stream>>>(xb, W1b, nullptr, nullptr, 1,
                                                  deg, cvec, h, N);

    for (int i = 1; i < HOP; ++i) {
        int last = (i == HOP - 1);
        // sagg = A . h  (gather-sum of previous embedding)
        aggregate_sum<<<(N + 3) / 4, 256, 0, stream>>>(h, off, colss, sagg, N);
        // dst = relu(xb@W1[i]^T + sagg@W2[i]^T + deg*c_i)
        if (last)
            gemm_pairs<1, 0><<<gblocks, 256, 0, stream>>>(xb, W1b + (size_t)i * H * H,
                                                          sagg, W2b + (size_t)i * H * H,
                                                          2, deg, cvec + i * H, out, N);
        else
            gemm_pairs<1, 1><<<gblocks, 256, 0, stream>>>(xb, W1b + (size_t)i * H * H,
                                                          sagg, W2b + (size_t)i * H * H,
                                                          2, deg, cvec + i * H, h, N);
    }
}